// Round 1
// baseline (172.886 us; speedup 1.0000x reference)
//
#include <hip/hip_runtime.h>

// out[p*B + b, o] = x[b, perm[indices[p]][o]]  where T[i] = eye(D)[perm[i]]
// (T[p][o][d] == 1 iff d == perm[p][o])
//
// Strategy: extract the combined permutation table (8 x 1024 ints, 32 KB in d_ws),
// then do a pure gather: LDS-stage each x row, coalesced float4 writes.

#define NUM_P 8
#define BATCH 4096
#define DIM   1024

// One wave (64 lanes) per output row (p, o): scan T[indices[p]][o][:] for the 1.0.
__global__ __launch_bounds__(256) void extract_perm_kernel(
        const float* __restrict__ T,
        const int* __restrict__ indices,
        int* __restrict__ perm) {
    int wave = (blockIdx.x << 2) | (threadIdx.x >> 6);  // 4 waves/block
    int lane = threadIdx.x & 63;
    int p = wave >> 10;          // output slot 0..7
    int o = wave & 1023;         // row within the permutation matrix
    int src = indices[p];        // which T block feeds output slot p
    const float4* row = (const float4*)(T + ((size_t)src * DIM + o) * DIM);

    int cand = 0;                // exactly one element of the row is 1.0
    #pragma unroll
    for (int k = 0; k < 4; ++k) {
        float4 v = row[lane + k * 64];       // coalesced: 16B/lane
        int d0 = (lane + k * 64) * 4;
        if (v.x > 0.5f) cand = d0;
        if (v.y > 0.5f) cand = d0 + 1;
        if (v.z > 0.5f) cand = d0 + 2;
        if (v.w > 0.5f) cand = d0 + 3;
    }
    // wave-wide max reduce (losers hold 0, winner holds the index)
    #pragma unroll
    for (int off = 32; off >= 1; off >>= 1)
        cand = max(cand, __shfl_xor(cand, off));
    if (lane == 0) perm[p * DIM + o] = cand;
}

// One block per batch row b: stage x[b] (4 KB) in LDS, emit all 8 permuted
// copies with coalesced float4 writes.
__global__ __launch_bounds__(256) void permute_gather_kernel(
        const float* __restrict__ x,
        const int* __restrict__ perm,
        float* __restrict__ out) {
    __shared__ float xs[DIM];
    const int b = blockIdx.x;
    const int tid = threadIdx.x;

    ((float4*)xs)[tid] = ((const float4*)(x + (size_t)b * DIM))[tid];
    __syncthreads();

    #pragma unroll
    for (int p = 0; p < NUM_P; ++p) {
        int4 idx = ((const int4*)(perm + p * DIM))[tid];   // coalesced, L1-hot
        float4 v;
        v.x = xs[idx.x];
        v.y = xs[idx.y];
        v.z = xs[idx.z];
        v.w = xs[idx.w];
        ((float4*)(out + ((size_t)(p * BATCH + b)) * DIM))[tid] = v;
    }
}

extern "C" void kernel_launch(void* const* d_in, const int* in_sizes, int n_in,
                              void* d_out, int out_size, void* d_ws, size_t ws_size,
                              hipStream_t stream) {
    const float* x       = (const float*)d_in[0];
    const float* T       = (const float*)d_in[1];
    const int*   indices = (const int*)d_in[2];
    float*       out     = (float*)d_out;
    int*         perm    = (int*)d_ws;   // 8*1024*4 = 32 KB scratch

    // 8192 rows, one wave each, 4 waves per 256-thread block -> 2048 blocks
    extract_perm_kernel<<<(NUM_P * DIM) / 4, 256, 0, stream>>>(T, indices, perm);
    permute_gather_kernel<<<BATCH, 256, 0, stream>>>(x, perm, out);
}